// Round 12
// baseline (4400.236 us; speedup 1.0000x reference)
//
#include <hip/hip_runtime.h>
#include <math.h>

#define B 8
#define S 128
#define D 512
#define M 4
#define BS 1024
#define BSD 524288          // B*S*D
#define DEPTH 16
#define THRESH 0.9999f
#define EPS 1e-6f
#define SCALE 0.04419417382415922f   // D^-0.5

typedef float floatx4 __attribute__((ext_vector_type(4)));
typedef short s8v __attribute__((ext_vector_type(8)));
typedef unsigned short us4 __attribute__((ext_vector_type(4)));

__device__ __forceinline__ unsigned short f2bf(float f) {
  unsigned int u = __float_as_uint(f);
  u += 0x7FFFu + ((u >> 16) & 1u);          // round-to-nearest-even
  return (unsigned short)(u >> 16);
}
__device__ __forceinline__ float bf2f(unsigned short h) {
  return __uint_as_float((unsigned int)h << 16);
}

// ---------------- workspace layout (float-slot offsets) ----------------
#define OFF_ZR   0
#define OFF_ZI   (1*BSD)
#define OFF_AR   (2*BSD)
#define OFF_AI   (3*BSD)
#define OFF_OR   (4*BSD)            // [M][B][S][D] fp32 = 4*BSD
#define OFF_OI   (8*BSD)
#define OFF_FEAT (12*BSD)           // 65536
#define OFF_GWP  (12*BSD + 65536)   // 8192
#define OFF_H0   (12*BSD + 73728)
#define OFF_H1   (12*BSD + 77824)
#define OFF_CUM  (12*BSD + 81920)   // 8
#define OFF_W    (12*BSD + 81928)   // 32
#define OFF_WT   (12*BSD + 81960)   // 8
#define OFF_CUM2 (12*BSD + 81968)   // 8
// bf16 annex (slots)
#define OFF_XH   (12*BSD + 90112)           // xcat hi [1024][1024] = 1 BSD
#define OFF_XL   (OFF_XH + 1*BSD)
#define OFF_WH   (OFF_XH + 2*BSD)           // 24 planes [512][512] hi = 6 BSD
#define OFF_WL   (OFF_XH + 8*BSD)
#define OFF_QCH  (OFF_XH + 14*BSD)          // Qcat hi [M][1024][1024] = 4 BSD
#define OFF_QCL  (OFF_XH + 18*BSD)
#define OFF_KCH  (OFF_XH + 22*BSD)
#define OFF_KCL  (OFF_XH + 26*BSD)
#define OFF_VTH  (OFF_XH + 30*BSD)          // Vt hi [2ri][M][512][1024] = 4 BSD
#define OFF_VTL  (OFF_XH + 34*BSD)
#define OFF_PH   (OFF_XH + 38*BSD)          // P hi [32][128][128] = 262144 slots
#define OFF_PL   (OFF_PH + 262144)
// end ~= 107.3 MB (R6/R8 proven)

// ---------------- init: fp32 carry + bf16 hi/lo Xcat + zero FEAT/GWP/CUMs ----------------
__global__ __launch_bounds__(256) void k_init(const float* __restrict__ xr,
                                              const float* __restrict__ xi,
                                              float* __restrict__ ws) {
  unsigned short* xh = (unsigned short*)(ws + OFF_XH);
  unsigned short* xl = (unsigned short*)(ws + OFF_XL);
  int i4 = blockIdx.x * 256 + threadIdx.x;      // BSD/4
  float4 a = ((const float4*)xr)[i4];
  float4 b = ((const float4*)xi)[i4];
  ((float4*)(ws + OFF_ZR))[i4] = a;
  ((float4*)(ws + OFF_ZI))[i4] = b;
  float4 z = {0.f, 0.f, 0.f, 0.f};
  ((float4*)(ws + OFF_AR))[i4] = z;
  ((float4*)(ws + OFF_AI))[i4] = z;
  int row = i4 >> 7;
  int d4 = (i4 & 127) * 4;
  float av[4] = {a.x, a.y, a.z, a.w}, bv[4] = {b.x, b.y, b.z, b.w};
  us4 hh, hl;
#pragma unroll
  for (int j = 0; j < 4; ++j) {
    unsigned short h = f2bf(av[j]); hh[j] = h; hl[j] = f2bf(av[j] - bf2f(h));
  }
  *(us4*)(xh + (size_t)row * 1024 + d4) = hh;
  *(us4*)(xl + (size_t)row * 1024 + d4) = hl;
#pragma unroll
  for (int j = 0; j < 4; ++j) {
    unsigned short h = f2bf(bv[j]); hh[j] = h; hl[j] = f2bf(bv[j] - bf2f(h));
  }
  *(us4*)(xh + (size_t)row * 1024 + 512 + d4) = hh;
  *(us4*)(xl + (size_t)row * 1024 + 512 + d4) = hl;
  if (i4 < (B * D) / 4) {
    ((float4*)(ws + OFF_H0))[i4] = z;
    ((float4*)(ws + OFF_H1))[i4] = z;
  }
  if (i4 < 16384) ((float4*)(ws + OFF_FEAT))[i4] = z;
  if (i4 < 2048)  ((float4*)(ws + OFF_GWP))[i4] = z;
  if (i4 < B) { ws[OFF_CUM + i4] = 0.f; ws[OFF_CUM2 + i4] = 0.f; }
}

// ---------------- weight prep (R6, proven) ----------------
__global__ __launch_bounds__(256) void k_wprep(const float* __restrict__ Wqr,
                                               const float* __restrict__ Wqi,
                                               const float* __restrict__ Wkr,
                                               const float* __restrict__ Wki,
                                               const float* __restrict__ Wvr,
                                               const float* __restrict__ Wvi,
                                               float* __restrict__ ws) {
  __shared__ float lt[64][65];
  unsigned short* wh = (unsigned short*)(ws + OFF_WH);
  unsigned short* wl = (unsigned short*)(ws + OFF_WL);
  int z = blockIdx.z, m = z / 6, idx = z % 6;
  const float* Wsrc;
  switch (idx) {
    case 0:  Wsrc = Wqr; break;
    case 1:  Wsrc = Wqi; break;
    case 2:  Wsrc = Wkr; break;
    case 3:  Wsrc = Wki; break;
    case 4:  Wsrc = Wvr; break;
    default: Wsrc = Wvi; break;
  }
  Wsrc += (size_t)m * D * D;
  int k0 = blockIdx.x * 64, n0 = blockIdx.y * 64;
  int tx = threadIdx.x & 63, ty = threadIdx.x >> 6;
#pragma unroll
  for (int i = 0; i < 16; ++i) {
    int kl = ty + i * 4;
    lt[kl][tx] = Wsrc[(size_t)(k0 + kl) * D + n0 + tx];
  }
  __syncthreads();
  unsigned short* whp = wh + (size_t)z * 262144;
  unsigned short* wlp = wl + (size_t)z * 262144;
#pragma unroll
  for (int i = 0; i < 16; ++i) {
    int nl = ty + i * 4;
    float v = lt[tx][nl];
    unsigned short h = f2bf(v);
    whp[(size_t)(n0 + nl) * 512 + k0 + tx] = h;
    wlp[(size_t)(n0 + nl) * 512 + k0 + tx] = f2bf(v - bf2f(h));
  }
}

// ---------------- gwp (pre-loop only) ----------------
__global__ __launch_bounds__(256) void k_gwp(const float* __restrict__ zr,
                                             const float* __restrict__ zi,
                                             float* __restrict__ gwp) {
  int idx = blockIdx.x * 256 + threadIdx.x;
  int b = idx >> 10;
  int f = idx & 1023;
  const float* src = (f < D) ? (zr + b * S * D + f) : (zi + b * S * D + (f - D));
  float s = 0.f;
#pragma unroll 8
  for (int ss = 0; ss < S; ++ss) s += src[ss * D];
  gwp[idx] = s * (1.0f / S);
}

// ---------------- GRU: k-split reduction GEMM (R7, proven) ----------------
__global__ __launch_bounds__(256) void k_gru(const float* __restrict__ gwp,
                                             const float* __restrict__ hold,
                                             float* __restrict__ hnew,
                                             const float* __restrict__ Wih,
                                             const float* __restrict__ Whh,
                                             const float* __restrict__ bih,
                                             const float* __restrict__ bhh) {
  __shared__ float xbuf[1024];
  __shared__ float hbuf[512];
  __shared__ float red[4][64][4];
  int b = blockIdx.y;
  int t = threadIdx.x;
  int td = t & 63, ks = t >> 6;
  int c0 = blockIdx.x * 64;
  for (int f = t; f < 1024; f += 256) xbuf[f] = gwp[b * 1024 + f];
  for (int d2 = t; d2 < 512; d2 += 256) hbuf[d2] = hold[b * 512 + d2];
  __syncthreads();
  float accR = 0.f, accZ = 0.f, accXn = 0.f, accHn = 0.f;
  int kbeg = ks * 384, kend = kbeg + 384;
#pragma unroll 4
  for (int kk = kbeg; kk < kend; ++kk) {
    bool ih = kk < 1024;
    float x = ih ? xbuf[kk] : hbuf[kk - 1024];
    const float* base = ih ? (Wih + (size_t)kk * 1536) : (Whh + (size_t)(kk - 1024) * 1536);
    float wr = base[c0 + td];
    float wz = base[512 + c0 + td];
    float wn = base[1024 + c0 + td];
    accR += x * wr;
    accZ += x * wz;
    if (ih) accXn += x * wn; else accHn += x * wn;
  }
  red[ks][td][0] = accR;
  red[ks][td][1] = accZ;
  red[ks][td][2] = accXn;
  red[ks][td][3] = accHn;
  __syncthreads();
  if (t < 64) {
    int c = c0 + t;
    float r_ = 0.f, z_ = 0.f, xn = 0.f, hn = 0.f;
#pragma unroll
    for (int s = 0; s < 4; ++s) {
      r_ += red[s][t][0]; z_ += red[s][t][1]; xn += red[s][t][2]; hn += red[s][t][3];
    }
    r_ += bih[c] + bhh[c];
    z_ += bih[512 + c] + bhh[512 + c];
    xn += bih[1024 + c];
    hn += bhh[1024 + c];
    float r = 1.f / (1.f + expf(-r_));
    float z = 1.f / (1.f + expf(-z_));
    float n = tanhf(xn + r * hn);
    hnew[b * 512 + c] = (1.f - z) * n + z * hbuf[c];
  }
}

// ---------------- QKV: bf16x3 MFMA; Q/K -> Qcat/Kcat hi/lo, V -> Vt hi/lo (R8, proven) ----------------
__global__ __launch_bounds__(256) void k_qkv(float* __restrict__ ws) {
  __shared__ __align__(16) unsigned short Ah[128 * 32], Al[128 * 32];
  __shared__ __align__(16) unsigned short Bh[128 * 32], Bl[128 * 32];
  const unsigned short* xh = (const unsigned short*)(ws + OFF_XH);
  const unsigned short* xl = (const unsigned short*)(ws + OFF_XL);
  const unsigned short* wh = (const unsigned short*)(ws + OFF_WH);
  const unsigned short* wl = (const unsigned short*)(ws + OFF_WL);
  int g = blockIdx.z, m = g / 6, w6 = g % 6;
  bool qk = (w6 < 4);
  int pair = (w6 >> 1) * 2;
  int p1 = m * 6 + pair + (w6 & 1);
  int p2 = m * 6 + pair + ((w6 & 1) ^ 1);
  unsigned int xmask = (w6 & 1) ? 0u : 0x80008000u;
  const unsigned short* PH1 = wh + (size_t)p1 * 262144;
  const unsigned short* PL1 = wl + (size_t)p1 * 262144;
  const unsigned short* PH2 = wh + (size_t)p2 * 262144;
  const unsigned short* PL2 = wl + (size_t)p2 * 262144;

  int row0 = qk ? blockIdx.y * 128 : blockIdx.x * 128;
  int col0 = qk ? blockIdx.x * 128 : blockIdx.y * 128;
  int wb = qk ? col0 : row0;
  int xb = qk ? row0 : col0;
  int t = threadIdx.x, lane = t & 63, w = t >> 6;
  int wr = w >> 1, wc = w & 1;
  int q = lane >> 4, r = lane & 15;
  int srow = t >> 2;
  int skoff = (t & 3) * 8;
  size_t wrow1 = (size_t)(wb + srow) * 512 + skoff;
  size_t wrow2 = (size_t)(wb + 64 + srow) * 512 + skoff;
  size_t xrow1 = (size_t)(xb + srow) * 1024 + skoff;
  size_t xrow2 = (size_t)(xb + 64 + srow) * 1024 + skoff;

  floatx4 acc[4][4];
#pragma unroll
  for (int i = 0; i < 4; ++i)
#pragma unroll
    for (int j = 0; j < 4; ++j) acc[i][j] = (floatx4){0.f, 0.f, 0.f, 0.f};

  for (int k0 = 0; k0 < 1024; k0 += 32) {
    const unsigned short *WgH, *WgL;
    unsigned int xm;
    int kk = k0;
    if (k0 < 512) { WgH = PH1; WgL = PL1; xm = 0u; }
    else          { WgH = PH2; WgL = PL2; xm = xmask; kk = k0 - 512; }
    uint4 w0h = *(const uint4*)(WgH + wrow1 + kk);
    uint4 w1h = *(const uint4*)(WgH + wrow2 + kk);
    uint4 w0l = *(const uint4*)(WgL + wrow1 + kk);
    uint4 w1l = *(const uint4*)(WgL + wrow2 + kk);
    w0h.x ^= xm; w0h.y ^= xm; w0h.z ^= xm; w0h.w ^= xm;
    w1h.x ^= xm; w1h.y ^= xm; w1h.z ^= xm; w1h.w ^= xm;
    w0l.x ^= xm; w0l.y ^= xm; w0l.z ^= xm; w0l.w ^= xm;
    w1l.x ^= xm; w1l.y ^= xm; w1l.z ^= xm; w1l.w ^= xm;
    uint4 x0h = *(const uint4*)(xh + xrow1 + k0);
    uint4 x1h = *(const uint4*)(xh + xrow2 + k0);
    uint4 x0l = *(const uint4*)(xl + xrow1 + k0);
    uint4 x1l = *(const uint4*)(xl + xrow2 + k0);
    if (qk) {
      *(uint4*)(Ah + srow * 32 + skoff) = x0h;
      *(uint4*)(Ah + (64 + srow) * 32 + skoff) = x1h;
      *(uint4*)(Al + srow * 32 + skoff) = x0l;
      *(uint4*)(Al + (64 + srow) * 32 + skoff) = x1l;
      *(uint4*)(Bh + srow * 32 + skoff) = w0h;
      *(uint4*)(Bh + (64 + srow) * 32 + skoff) = w1h;
      *(uint4*)(Bl + srow * 32 + skoff) = w0l;
      *(uint4*)(Bl + (64 + srow) * 32 + skoff) = w1l;
    } else {
      *(uint4*)(Ah + srow * 32 + skoff) = w0h;
      *(uint4*)(Ah + (64 + srow) * 32 + skoff) = w1h;
      *(uint4*)(Al + srow * 32 + skoff) = w0l;
      *(uint4*)(Al + (64 + srow) * 32 + skoff) = w1l;
      *(uint4*)(Bh + srow * 32 + skoff) = x0h;
      *(uint4*)(Bh + (64 + srow) * 32 + skoff) = x1h;
      *(uint4*)(Bl + srow * 32 + skoff) = x0l;
      *(uint4*)(Bl + (64 + srow) * 32 + skoff) = x1l;
    }
    __syncthreads();
    s8v ah[4], al[4], bh[4], bl[4];
#pragma unroll
    for (int i = 0; i < 4; ++i) {
      int ro = (wr * 64 + i * 16 + r) * 32 + q * 8;
      ah[i] = *(const s8v*)((const short*)Ah + ro);
      al[i] = *(const s8v*)((const short*)Al + ro);
    }
#pragma unroll
    for (int j = 0; j < 4; ++j) {
      int ro = (wc * 64 + j * 16 + r) * 32 + q * 8;
      bh[j] = *(const s8v*)((const short*)Bh + ro);
      bl[j] = *(const s8v*)((const short*)Bl + ro);
    }
#pragma unroll
    for (int i = 0; i < 4; ++i)
#pragma unroll
      for (int j = 0; j < 4; ++j) {
        acc[i][j] = __builtin_amdgcn_mfma_f32_16x16x32_bf16(ah[i], bh[j], acc[i][j], 0, 0, 0);
        acc[i][j] = __builtin_amdgcn_mfma_f32_16x16x32_bf16(ah[i], bl[j], acc[i][j], 0, 0, 0);
        acc[i][j] = __builtin_amdgcn_mfma_f32_16x16x32_bf16(al[i], bh[j], acc[i][j], 0, 0, 0);
      }
    __syncthreads();
  }
  unsigned short *dh, *dl;
  size_t base;
  int half = 0;
  if (qk) {
    if (w6 < 2) { dh = (unsigned short*)(ws + OFF_QCH); dl = (unsigned short*)(ws + OFF_QCL); }
    else        { dh = (unsigned short*)(ws + OFF_KCH); dl = (unsigned short*)(ws + OFF_KCL); }
    half = (w6 & 1) * 512;
    base = (size_t)m * 1024 * 1024;
  } else {
    dh = (unsigned short*)(ws + OFF_VTH);
    dl = (unsigned short*)(ws + OFF_VTL);
    base = (size_t)((w6 & 1) * 4 + m) * 512 * 1024;
  }
#pragma unroll
  for (int i = 0; i < 4; ++i)
#pragma unroll
    for (int j = 0; j < 4; ++j) {
      int rowb = row0 + wr * 64 + i * 16 + q * 4;
      int colb = col0 + wc * 64 + j * 16 + r;
#pragma unroll
      for (int reg = 0; reg < 4; ++reg) {
        float v = acc[i][j][reg];
        unsigned short h = f2bf(v);
        size_t idx = base + (size_t)(rowb + reg) * 1024 + half + colb;
        dh[idx] = h;
        dl[idx] = f2bf(v - bf2f(h));
      }
    }
}

// ---------------- attn: scores (bf16x3 MFMA) + softmax -> P hi/lo (R11, proven) ----------------
// grid 64 (mb*2 + rowhalf), 256 thr. 64x128 tile: 4 col-waves x (4 i-frag, 2 j-frag).
__global__ __launch_bounds__(256) void k_attn(float* __restrict__ ws) {
  __shared__ __align__(16) unsigned short Ah[64 * 32], Al[64 * 32];
  __shared__ __align__(16) unsigned short Bh[128 * 32], Bl[128 * 32];
  __shared__ float rmax[64][4];
  __shared__ float rsum[64][4];
  const unsigned short* qch = (const unsigned short*)(ws + OFF_QCH);
  const unsigned short* qcl = (const unsigned short*)(ws + OFF_QCL);
  const unsigned short* kch = (const unsigned short*)(ws + OFF_KCH);
  const unsigned short* kcl = (const unsigned short*)(ws + OFF_KCL);
  unsigned short* ph = (unsigned short*)(ws + OFF_PH);
  unsigned short* pl = (unsigned short*)(ws + OFF_PL);
  int blk = blockIdx.x, mb = blk >> 1, half = blk & 1;
  size_t gbase = (size_t)mb * 128 * 1024;
  int t = threadIdx.x, lane = t & 63, wc = t >> 6;
  int q = lane >> 4, r = lane & 15;
  int srow = t >> 2;                 // 0..63
  int skoff = (t & 3) * 8;
  size_t arow = gbase + (size_t)(half * 64 + srow) * 1024 + skoff;  // Q rows (64)
  size_t brow1 = gbase + (size_t)srow * 1024 + skoff;               // K rows (all 128)
  size_t brow2 = gbase + (size_t)(64 + srow) * 1024 + skoff;

  floatx4 acc[4][2];
#pragma unroll
  for (int i = 0; i < 4; ++i)
#pragma unroll
    for (int j = 0; j < 2; ++j) acc[i][j] = (floatx4){0.f, 0.f, 0.f, 0.f};

  for (int k0 = 0; k0 < 1024; k0 += 32) {
    uint4 a0h = *(const uint4*)(qch + arow + k0);
    uint4 a0l = *(const uint4*)(qcl + arow + k0);
    uint4 b0h = *(const uint4*)(kch + brow1 + k0);
    uint4 b1h = *(const uint4*)(kch + brow2 + k0);
    uint4 b0l = *(const uint4*)(kcl + brow1 + k0);
    uint4 b1l = *(const uint4*)(kcl + brow2 + k0);
    *(uint4*)(Ah + srow * 32 + skoff) = a0h;
    *(uint4*)(Al + srow * 32 + skoff) = a0l;
    *(uint4*)(Bh + srow * 32 + skoff) = b0h;
    *(uint4*)(Bh + (64 + srow) * 32 + skoff) = b1h;
    *(uint4*)(Bl + srow * 32 + skoff) = b0l;
    *(uint4*)(Bl + (64 + srow) * 32 + skoff) = b1l;
    __syncthreads();
    s8v ah[4], al[4], bh[2], bl[2];
#pragma unroll
    for (int i = 0; i < 4; ++i) {
      int ro = (i * 16 + r) * 32 + q * 8;
      ah[i] = *(const s8v*)((const short*)Ah + ro);
      al[i] = *(const s8v*)((const short*)Al + ro);
    }
#pragma unroll
    for (int j = 0; j < 2; ++j) {
      int ro = (wc * 32 + j * 16 + r) * 32 + q * 8;
      bh[j] = *(const s8v*)((const short*)Bh + ro);
      bl[j] = *(const s8v*)((const short*)Bl + ro);
    }
#pragma unroll
    for (int i = 0; i < 4; ++i)
#pragma unroll
      for (int j = 0; j < 2; ++j) {
        acc[i][j] = __builtin_amdgcn_mfma_f32_16x16x32_bf16(ah[i], bh[j], acc[i][j], 0, 0, 0);
        acc[i][j] = __builtin_amdgcn_mfma_f32_16x16x32_bf16(ah[i], bl[j], acc[i][j], 0, 0, 0);
        acc[i][j] = __builtin_amdgcn_mfma_f32_16x16x32_bf16(al[i], bh[j], acc[i][j], 0, 0, 0);
      }
    __syncthreads();
  }
#pragma unroll
  for (int i = 0; i < 4; ++i)
#pragma unroll
    for (int j = 0; j < 2; ++j)
#pragma unroll
      for (int reg = 0; reg < 4; ++reg) acc[i][j][reg] *= SCALE;
#pragma unroll
  for (int i = 0; i < 4; ++i)
#pragma unroll
    for (int reg = 0; reg < 4; ++reg) {
      float mx = fmaxf(acc[i][0][reg], acc[i][1][reg]);
      for (int o = 1; o < 16; o <<= 1) mx = fmaxf(mx, __shfl_xor(mx, o));
      if (r == 0) rmax[i * 16 + q * 4 + reg][wc] = mx;
    }
  __syncthreads();
#pragma unroll
  for (int i = 0; i < 4; ++i)
#pragma unroll
    for (int reg = 0; reg < 4; ++reg) {
      int row = i * 16 + q * 4 + reg;
      float gmx = fmaxf(fmaxf(rmax[row][0], rmax[row][1]),
                        fmaxf(rmax[row][2], rmax[row][3]));
      float sm = 0.f;
#pragma unroll
      for (int j = 0; j < 2; ++j) {
        float e = __expf(acc[i][j][reg] - gmx);
        acc[i][j][reg] = e;
        sm += e;
      }
      for (int o = 1; o < 16; o <<= 1) sm += __shfl_xor(sm, o);
      if (r == 0) rsum[row][wc] = sm;
    }
  __syncthreads();
#pragma unroll
  for (int i = 0; i < 4; ++i)
#pragma unroll
    for (int reg = 0; reg < 4; ++reg) {
      int row = i * 16 + q * 4 + reg;
      float inv = 1.f / (rsum[row][0] + rsum[row][1] + rsum[row][2] + rsum[row][3]);
      size_t rb = (size_t)(mb * 128 + half * 64 + row) * 128;
#pragma unroll
      for (int j = 0; j < 2; ++j) {
        float p = acc[i][j][reg] * inv;
        unsigned short h = f2bf(p);
        size_t idx = rb + wc * 32 + j * 16 + r;
        ph[idx] = h;
        pl[idx] = f2bf(p - bf2f(h));
      }
    }
}

// ---------------- PV: O = P @ Vt^T (bf16x3 MFMA), fp32 out — 256-block split ----------------
// grid (8, 32): x = et*2 + shalf; et = e-tile (0..3), shalf = row half. 64s x 128e per block.
__global__ __launch_bounds__(256) void k_pv(float* __restrict__ ws) {
  __shared__ __align__(16) unsigned short Ph_[64 * 32], Pl_[64 * 32];
  __shared__ __align__(16) unsigned short VrH[128 * 32], VrL[128 * 32];
  __shared__ __align__(16) unsigned short ViH[128 * 32], ViL[128 * 32];
  const unsigned short* ph = (const unsigned short*)(ws + OFF_PH);
  const unsigned short* pl = (const unsigned short*)(ws + OFF_PL);
  const unsigned short* vth = (const unsigned short*)(ws + OFF_VTH);
  const unsigned short* vtl = (const unsigned short*)(ws + OFF_VTL);
  int mb = blockIdx.y, m = mb >> 3, b = mb & 7;
  int et = blockIdx.x >> 1, sh = blockIdx.x & 1;
  int col0 = et * 128;
  int t = threadIdx.x, lane = t & 63, w = t >> 6;
  int wr = w >> 1, wc = w & 1;
  int q = lane >> 4, r = lane & 15;
  int srow = t >> 2;
  int skoff = (t & 3) * 8;
  size_t prow = (size_t)(mb * 128 + sh * 64 + srow) * 128 + skoff;
  size_t vbr1 = ((size_t)(m * 512) + col0 + srow) * 1024 + b * 128 + skoff;
  size_t vbr2 = ((size_t)(m * 512) + col0 + 64 + srow) * 1024 + b * 128 + skoff;
  size_t vplane_i = (size_t)4 * 512 * 1024;

  floatx4 accR[2][4], accI[2][4];
#pragma unroll
  for (int i = 0; i < 2; ++i)
#pragma unroll
    for (int j = 0; j < 4; ++j) {
      accR[i][j] = (floatx4){0.f, 0.f, 0.f, 0.f};
      accI[i][j] = (floatx4){0.f, 0.f, 0.f, 0.f};
    }

  for (int k0 = 0; k0 < 128; k0 += 32) {
    *(uint4*)(Ph_ + srow * 32 + skoff) = *(const uint4*)(ph + prow + k0);
    *(uint4*)(Pl_ + srow * 32 + skoff) = *(const uint4*)(pl + prow + k0);
    *(uint4*)(VrH + srow * 32 + skoff) = *(const uint4*)(vth + vbr1 + k0);
    *(uint4*)(VrH + (64 + srow) * 32 + skoff) = *(const uint4*)(vth + vbr2 + k0);
    *(uint4*)(VrL + srow * 32 + skoff) = *(const uint4*)(vtl + vbr1 + k0);
    *(uint4*)(VrL + (64 + srow) * 32 + skoff) = *(const uint4*)(vtl + vbr2 + k0);
    *(uint4*)(ViH + srow * 32 + skoff) = *(const uint4*)(vth + vplane_i + vbr1 + k0);
    *(uint4*)(ViH + (64 + srow) * 32 + skoff) = *(const uint4*)(vth + vplane_i + vbr2 + k0);
    *(uint4*)(ViL + srow * 32 + skoff) = *(const uint4*)(vtl + vplane_i + vbr1 + k0);
    *(uint4*)(ViL + (64 + srow) * 32 + skoff) = *(const uint4*)(vtl + vplane_i + vbr2 + k0);
    __syncthreads();
    s8v ah[2], al[2];
#pragma unroll
    for (int i = 0; i < 2; ++i) {
      int ro = (wr * 32 + i * 16 + r) * 32 + q * 8;
      ah[i] = *(const s8v*)((const short*)Ph_ + ro);
      al[i] = *(const s8v*)((const short*)Pl_ + ro);
    }
#pragma unroll
    for (int j = 0; j < 4; ++j) {
      int ro = (wc * 64 + j * 16 + r) * 32 + q * 8;
      s8v vrh = *(const s8v*)((const short*)VrH + ro);
      s8v vrl = *(const s8v*)((const short*)VrL + ro);
      s8v vih = *(const s8v*)((const short*)ViH + ro);
      s8v vil = *(const s8v*)((const short*)ViL + ro);
#pragma unroll
      for (int i = 0; i < 2; ++i) {
        accR[i][j] = __builtin_amdgcn_mfma_f32_16x16x32_bf16(ah[i], vrh, accR[i][j], 0, 0, 0);
        accR[i][j] = __builtin_amdgcn_mfma_f32_16x16x32_bf16(ah[i], vrl, accR[i][j], 0, 0, 0);
        accR[i][j] = __builtin_amdgcn_mfma_f32_16x16x32_bf16(al[i], vrh, accR[i][j], 0, 0, 0);
        accI[i][j] = __builtin_amdgcn_mfma_f32_16x16x32_bf16(ah[i], vih, accI[i][j], 0, 0, 0);
        accI[i][j] = __builtin_amdgcn_mfma_f32_16x16x32_bf16(ah[i], vil, accI[i][j], 0, 0, 0);
        accI[i][j] = __builtin_amdgcn_mfma_f32_16x16x32_bf16(al[i], vih, accI[i][j], 0, 0, 0);
      }
    }
    __syncthreads();
  }
  float* orp = ws + OFF_OR + (size_t)mb * 128 * 512;
  float* oip = ws + OFF_OI + (size_t)mb * 128 * 512;
#pragma unroll
  for (int i = 0; i < 2; ++i)
#pragma unroll
    for (int j = 0; j < 4; ++j) {
      int rowb = sh * 64 + wr * 32 + i * 16 + q * 4;
      int colb = col0 + wc * 64 + j * 16 + r;
#pragma unroll
      for (int reg = 0; reg < 4; ++reg) {
        orp[(size_t)(rowb + reg) * 512 + colb] = accR[i][j][reg];
        oip[(size_t)(rowb + reg) * 512 + colb] = accI[i][j][reg];
      }
    }
}

// ---------------- ModReLU + ComplexLayerNorm + feat partials — 256-block split ----------------
// grid 256 (mb*8+grp), 256 thr = 4 waves; wave w handles rows s = grp*16 + it*4 + w (it<4).
__global__ __launch_bounds__(256) void k_modlnfeat(float* __restrict__ ws,
                                                   const float* __restrict__ mod_bias,
                                                   const float* __restrict__ ln_scale,
                                                   const float* __restrict__ ln_shift) {
  int blk = blockIdx.x;
  int mb = blk >> 3, grp = blk & 7;
  int m = mb >> 3;
  int t = threadIdx.x, w = t >> 6, l = t & 63;
  int e0 = l * 8;
  float mb_[8], lsc[8], lsh[8];
  *(float4*)&mb_[0] = *(const float4*)(mod_bias + m * 512 + e0);
  *(float4*)&mb_[4] = *(const float4*)(mod_bias + m * 512 + e0 + 4);
  *(float4*)&lsc[0] = *(const float4*)(ln_scale + m * 512 + e0);
  *(float4*)&lsc[4] = *(const float4*)(ln_scale + m * 512 + e0 + 4);
  *(float4*)&lsh[0] = *(const float4*)(ln_shift + m * 512 + e0);
  *(float4*)&lsh[4] = *(const float4*)(ln_shift + m * 512 + e0 + 4);
  float featR[8] = {}, featI[8] = {};
  for (int it = 0; it < 4; ++it) {
    int s = grp * 16 + it * 4 + w;
    float* orp = ws + OFF_OR + ((size_t)mb * 128 + s) * 512 + e0;
    float* oip = ws + OFF_OI + ((size_t)mb * 128 + s) * 512 + e0;
    float orv[8], oiv[8], magv[8];
    *(float4*)&orv[0] = *(const float4*)orp;
    *(float4*)&orv[4] = *(const float4*)(orp + 4);
    *(float4*)&oiv[0] = *(const float4*)oip;
    *(float4*)&oiv[4] = *(const float4*)(oip + 4);
    float sum = 0.f, sumsq = 0.f;
#pragma unroll
    for (int j = 0; j < 8; ++j) {
      float o_r = orv[j], o_i = oiv[j];
      float mag = sqrtf(o_r * o_r + o_i * o_i) + EPS;
      float g = fmaxf(mag + mb_[j], 0.f) / mag;
      o_r *= g; o_i *= g;
      orv[j] = o_r; oiv[j] = o_i;
      float mag2 = sqrtf(o_r * o_r + o_i * o_i) + EPS;
      magv[j] = mag2;
      sum += mag2;
      sumsq += mag2 * mag2;
    }
    for (int o = 1; o < 64; o <<= 1) {
      sum += __shfl_xor(sum, o);
      sumsq += __shfl_xor(sumsq, o);
    }
    float mu = sum * (1.f / D);
    float var = (sumsq - (float)D * mu * mu) * (1.f / (D - 1));
    float inv = 1.f / sqrtf(var + EPS);
#pragma unroll
    for (int j = 0; j < 8; ++j) {
      float nm = (magv[j] - mu) * inv * lsc[j] + lsh[j];
      float hyp = magv[j] - EPS;
      float cp, sp;
      if (hyp > 0.f) { cp = orv[j] / hyp; sp = oiv[j] / hyp; }
      else           { cp = 1.f;          sp = 0.f; }
      orv[j] = nm * cp;
      oiv[j] = nm * sp;
      featR[j] += orv[j];
      featI[j] += oiv[j];
    }
    *(float4*)orp = *(float4*)&orv[0];
    *(float4*)(orp + 4) = *(float4*)&orv[4];
    *(float4*)oip = *(float4*)&oiv[0];
    *(float4*)(oip + 4) = *(float4*)&oiv[4];
  }
  float* fb = ws + OFF_FEAT + (size_t)mb * 1024;
#pragma unroll
  for (int j = 0; j < 8; ++j) {
    atomicAdd(fb + e0 + j, featR[j] * (1.0f / S));
    atomicAdd(fb + 512 + e0 + j, featI[j] * (1.0f / S));
  }
}

// ---------------- wsel (R1) + zero FEAT/GWP for next step (R9) ----------------
__global__ __launch_bounds__(256) void k_wsel(float* __restrict__ ws,
                                              const float* __restrict__ hnew,
                                              const float* __restrict__ bias_W,
                                              const float* __restrict__ bias_b,
                                              const float* __restrict__ w_sal) {
  __shared__ float mb_s[B][M];
  __shared__ float sal_s[M][B];
  int t = threadIdx.x;
  int p = t >> 3, l = t & 7;
  {
    int b = p >> 2, m = p & 3;
    float s = 0.f;
    for (int d2 = l; d2 < D; d2 += 8) s += hnew[b * D + d2] * bias_W[d2 * M + m];
    for (int o = 1; o < 8; o <<= 1) s += __shfl_xor(s, o);
    if (l == 0) mb_s[b][m] = s + bias_b[m];
  }
  {
    int m = p >> 3, b = p & 7;
    float s = 0.f;
    for (int f = l; f < 2 * D; f += 8) s += ws[OFF_FEAT + (m * B + b) * 2 * D + f] * w_sal[m * 2 * D + f];
    for (int o = 1; o < 8; o <<= 1) s += __shfl_xor(s, o);
    if (l == 0) sal_s[m][b] = s;
  }
  __syncthreads();
  if (t < B) {
    int b = t;
    float lg[M], mx = -1e30f;
#pragma unroll
    for (int m = 0; m < M; ++m) { lg[m] = sal_s[m][b] + mb_s[b][m]; mx = fmaxf(mx, lg[m]); }
    float sm = 0.f;
#pragma unroll
    for (int m = 0; m < M; ++m) { lg[m] = expf(lg[m] - mx); sm += lg[m]; }
    float inv = 1.f / sm;
#pragma unroll
    for (int m = 0; m < M; ++m) ws[OFF_W + m * B + b] = lg[m] * inv;
  }
  float4 z4 = {0.f, 0.f, 0.f, 0.f};
  for (int i = t; i < 16384; i += 256) ((float4*)(ws + OFF_FEAT))[i] = z4;
  for (int i = t; i < 2048; i += 256) ((float4*)(ws + OFF_GWP))[i] = z4;
}

// ---------------- bcast (fp32 Z + bf16 Xcat) + gwp partial accumulation (R9) ----------------
__global__ __launch_bounds__(256) void k_bcast(float* __restrict__ ws) {
  __shared__ float pr[1024];
  unsigned short* xh = (unsigned short*)(ws + OFF_XH);
  unsigned short* xl = (unsigned short*)(ws + OFF_XL);
  int t = threadIdx.x;
  int i4 = blockIdx.x * 256 + t;
  int b = i4 >> 14;
  int l = t & 127;
  float w0 = ws[OFF_W + 0 * B + b], w1 = ws[OFF_W + 1 * B + b];
  float w2 = ws[OFF_W + 2 * B + b], w3 = ws[OFF_W + 3 * B + b];
  const float4* mr = (const float4*)(ws + OFF_OR);
  const float4* mi = (const float4*)(ws + OFF_OI);
  const int MS = BSD / 4;
  int row = i4 >> 7;
  int d4 = (i4 & 127) * 4;
  float4 r0 = mr[i4], r1 = mr[i4 + MS], r2 = mr[i4 + 2 * MS], r3 = mr[i4 + 3 * MS];
  float gvR[4];
  gvR[0] = w0 * r0.x + w1 * r1.x + w2 * r2.x + w3 * r3.x;
  gvR[1] = w0 * r0.y + w1 * r1.y + w2 * r2.y + w3 * r3.y;
  gvR[2] = w0 * r0.z + w1 * r1.z + w2 * r2.z + w3 * r3.z;
  gvR[3] = w0 * r0.w + w1 * r1.w + w2 * r2.w + w3 * r3.w;
  ((float4*)(ws + OFF_ZR))[i4] = (float4){gvR[0], gvR[1], gvR[2], gvR[3]};
  us4 hh, hl;
#pragma unroll
  for (int j = 0; j < 4; ++j) {
    unsigned short h = f2bf(gvR[j]); hh[j] = h; hl[j] = f2bf(gvR[j] - bf2f(h));
  }
  *(us4*)(xh + (size_t)row * 1024 + d4) = hh;
  *(us4*)(xl + (size_t)row * 1024 + d4) = hl;
  float4 s0 = mi[i4], s1 = mi[i4 + MS], s2 = mi[i4 + 2 * MS], s3 = mi[i4 + 3 * MS];
  float gvI[4];
  gvI[0] = w0 * s0.x + w1 * s1.x + w2 * s2.x + w3 * s3.x;
  gvI[1] = w0 * s0.y + w1 * s1.y + w2 * s2.y + w3 * s3.y;
  gvI[2] = w0 * s0.z + w1 * s1.z + w2 * s2.z + w3 * s3.z;
  gvI[3] = w0 * s0.w + w1 * s1.w + w2 * s2.w + w3 * s3.w;
  ((float4*)(ws + OFF_ZI))[i4] = (float4){gvI[0], gvI[1], gvI[2], gvI[3]};
#pragma unroll
  for (int j = 0; j < 4; ++j) {
    unsigned short h = f2bf(gvI[j]); hh[j] = h; hl[j] = f2bf(gvI[j] - bf2f(h));
  }
  *(us4*)(xh + (size_t)row * 1024 + 512 + d4) = hh;
  *(us4*)(xl + (size_t)row * 1024 + 512 + d4) = hl;
  if (t < 128) {
#pragma unroll
    for (int j = 0; j < 4; ++j) { pr[l * 4 + j] = gvR[j]; pr[512 + l * 4 + j] = gvI[j]; }
  }
  __syncthreads();
  if (t >= 128) {
#pragma unroll
    for (int j = 0; j < 4; ++j) { pr[l * 4 + j] += gvR[j]; pr[512 + l * 4 + j] += gvI[j]; }
  }
  __syncthreads();
  for (int pp = t; pp < 1024; pp += 256)
    atomicAdd(ws + OFF_GWP + b * 1024 + pp, pr[pp] * (1.0f / S));
}

// ---------------- halt + ACT accumulate (fused; cum double-buffered) (R9) ----------------
__global__ __launch_bounds__(256) void k_acchalt(float* __restrict__ ws,
                                                 const float* __restrict__ w_halt,
                                                 const float* __restrict__ b_halt,
                                                 const float* __restrict__ cumr,
                                                 float* __restrict__ cumw) {
  __shared__ float sred[4];
  int t = threadIdx.x;
  int i4 = blockIdx.x * 256 + t;
  int b = i4 >> 14;
  float4 g = *(const float4*)(ws + OFF_GWP + b * 1024 + t * 4);
  float4 wv = *(const float4*)(w_halt + t * 4);
  float s = g.x * wv.x + g.y * wv.y + g.z * wv.z + g.w * wv.w;
  for (int o = 1; o < 64; o <<= 1) s += __shfl_xor(s, o);
  if ((t & 63) == 0) sred[t >> 6] = s;
  __syncthreads();
  float tot = sred[0] + sred[1] + sred[2] + sred[3];
  float p = 1.f / (1.f + expf(-(tot + b_halt[0])));
  float cum = cumr[b];
  float still = (cum < THRESH) ? 1.f : 0.f;
  bool nh = ((cum + p) >= THRESH) && (cum < THRESH);
  float wt = (nh ? (1.f - cum) : p) * still;
  if (((blockIdx.x & 63) == 0) && t == 0) cumw[b] = cum + wt;
  float4 z = ((const float4*)(ws + OFF_ZR))[i4];
  float4 a = ((float4*)(ws + OFF_AR))[i4];
  a.x += wt * z.x; a.y += wt * z.y; a.z += wt * z.z; a.w += wt * z.w;
  ((float4*)(ws + OFF_AR))[i4] = a;
  z = ((const float4*)(ws + OFF_ZI))[i4];
  a = ((float4*)(ws + OFF_AI))[i4];
  a.x += wt * z.x; a.y += wt * z.y; a.z += wt * z.z; a.w += wt * z.w;
  ((float4*)(ws + OFF_AI))[i4] = a;
}

// ---------------- output (R1) ----------------
__global__ __launch_bounds__(256) void k_out(const float* __restrict__ ws,
                                             float* __restrict__ out) {
  int i4 = blockIdx.x * 256 + threadIdx.x;
  ((float4*)out)[i4] = ((const float4*)(ws + OFF_AR))[i4];
  ((float4*)out)[i4 + BSD / 4] = ((const float4*)(ws + OFF_AI))[i4];
}

extern "C" void kernel_launch(void* const* d_in, const int* in_sizes, int n_in,
                              void* d_out, int out_size, void* d_ws, size_t ws_size,
                              hipStream_t stream) {
  (void)in_sizes; (void)n_in; (void)out_size; (void)ws_size;
  const float* x_real  = (const float*)d_in[0];
  const float* x_imag  = (const float*)d_in[1];
  const float* Wq_r    = (const float*)d_in[2];
  const float* Wq_i    = (const float*)d_in[3];
  const float* Wk_r    = (const float*)d_in[4];
  const float* Wk_i    = (const float*)d_in[5];
  const float* Wv_r    = (const float*)d_in[6];
  const float* Wv_i    = (const float*)d_in[7];
  const float* mod_bias = (const float*)d_in[8];
  const float* ln_scale = (const float*)d_in[9];
  const float* ln_shift = (const float*)d_in[10];
  const float* w_sal   = (const float*)d_in[11];
  const float* gru_Wih = (const float*)d_in[12];
  const float* gru_Whh = (const float*)d_in[13];
  const float* gru_bih = (const float*)d_in[14];
  const float* gru_bhh = (const float*)d_in[15];
  const float* bias_W  = (const float*)d_in[16];
  const float* bias_b  = (const float*)d_in[17];
  const float* w_halt  = (const float*)d_in[18];
  const float* b_halt  = (const float*)d_in[19];
  float* ws = (float*)d_ws;
  float* out = (float*)d_out;

  k_wprep<<<dim3(8, 8, 24), 256, 0, stream>>>(Wq_r, Wq_i, Wk_r, Wk_i, Wv_r, Wv_i, ws);
  k_init<<<512, 256, 0, stream>>>(x_real, x_imag, ws);
  k_gwp<<<32, 256, 0, stream>>>(ws + OFF_ZR, ws + OFF_ZI, ws + OFF_GWP);
  for (int step = 0; step < DEPTH; ++step) {
    const float* hold = ws + ((step & 1) ? OFF_H1 : OFF_H0);
    float* hnew = ws + ((step & 1) ? OFF_H0 : OFF_H1);
    const float* cumr = ws + ((step & 1) ? OFF_CUM2 : OFF_CUM);
    float* cumw = ws + ((step & 1) ? OFF_CUM : OFF_CUM2);
    k_gru<<<dim3(8, 8), 256, 0, stream>>>(ws + OFF_GWP, hold, hnew,
                                          gru_Wih, gru_Whh, gru_bih, gru_bhh);
    k_qkv<<<dim3(4, 8, 24), 256, 0, stream>>>(ws);
    k_attn<<<64, 256, 0, stream>>>(ws);
    k_pv<<<dim3(8, 32), 256, 0, stream>>>(ws);
    k_modlnfeat<<<256, 256, 0, stream>>>(ws, mod_bias, ln_scale, ln_shift);
    k_wsel<<<1, 256, 0, stream>>>(ws, hnew, bias_W, bias_b, w_sal);
    k_bcast<<<512, 256, 0, stream>>>(ws);
    k_acchalt<<<512, 256, 0, stream>>>(ws, w_halt, b_halt, cumr, cumw);
  }
  k_out<<<512, 256, 0, stream>>>(ws, out);
}

// Round 13
// 4118.781 us; speedup vs baseline: 1.0683x; 1.0683x over previous
//
#include <hip/hip_runtime.h>
#include <math.h>

#define B 8
#define S 128
#define D 512
#define M 4
#define BS 1024
#define BSD 524288          // B*S*D
#define DEPTH 16
#define THRESH 0.9999f
#define EPS 1e-6f
#define SCALE 0.04419417382415922f   // D^-0.5

typedef float floatx4 __attribute__((ext_vector_type(4)));
typedef short s8v __attribute__((ext_vector_type(8)));
typedef unsigned short us4 __attribute__((ext_vector_type(4)));

__device__ __forceinline__ unsigned short f2bf(float f) {
  unsigned int u = __float_as_uint(f);
  u += 0x7FFFu + ((u >> 16) & 1u);          // round-to-nearest-even
  return (unsigned short)(u >> 16);
}
__device__ __forceinline__ float bf2f(unsigned short h) {
  return __uint_as_float((unsigned int)h << 16);
}

// ---------------- workspace layout (float-slot offsets) ----------------
#define OFF_ZR   0
#define OFF_ZI   (1*BSD)
#define OFF_AR   (2*BSD)
#define OFF_AI   (3*BSD)
#define OFF_OR   (4*BSD)            // [M][B][S][D] fp32 = 4*BSD
#define OFF_OI   (8*BSD)
#define OFF_FEAT (12*BSD)           // 65536
#define OFF_GWP  (12*BSD + 65536)   // 8192
#define OFF_H0   (12*BSD + 73728)
#define OFF_H1   (12*BSD + 77824)
#define OFF_CUM  (12*BSD + 81920)   // 8
#define OFF_W    (12*BSD + 81928)   // 32
#define OFF_WT   (12*BSD + 81960)   // 8
#define OFF_CUM2 (12*BSD + 81968)   // 8
// bf16 annex (slots)
#define OFF_XH   (12*BSD + 90112)           // xcat hi [1024][1024] = 1 BSD
#define OFF_XL   (OFF_XH + 1*BSD)
#define OFF_WH   (OFF_XH + 2*BSD)           // 24 planes [512][512] hi = 6 BSD
#define OFF_WL   (OFF_XH + 8*BSD)
#define OFF_QCH  (OFF_XH + 14*BSD)          // Qcat hi [M][1024][1024] = 4 BSD
#define OFF_QCL  (OFF_XH + 18*BSD)
#define OFF_KCH  (OFF_XH + 22*BSD)
#define OFF_KCL  (OFF_XH + 26*BSD)
#define OFF_VTH  (OFF_XH + 30*BSD)          // Vt hi [2ri][M][512][1024] = 4 BSD
#define OFF_VTL  (OFF_XH + 34*BSD)
#define OFF_PH   (OFF_XH + 38*BSD)          // P hi [32][128][128] = 262144 slots
#define OFF_PL   (OFF_PH + 262144)
// end ~= 107.3 MB (R6/R8 proven)

// ---------------- init: fp32 carry + bf16 hi/lo Xcat + zero FEAT/GWP/CUMs ----------------
__global__ __launch_bounds__(256) void k_init(const float* __restrict__ xr,
                                              const float* __restrict__ xi,
                                              float* __restrict__ ws) {
  unsigned short* xh = (unsigned short*)(ws + OFF_XH);
  unsigned short* xl = (unsigned short*)(ws + OFF_XL);
  int i4 = blockIdx.x * 256 + threadIdx.x;      // BSD/4
  float4 a = ((const float4*)xr)[i4];
  float4 b = ((const float4*)xi)[i4];
  ((float4*)(ws + OFF_ZR))[i4] = a;
  ((float4*)(ws + OFF_ZI))[i4] = b;
  float4 z = {0.f, 0.f, 0.f, 0.f};
  ((float4*)(ws + OFF_AR))[i4] = z;
  ((float4*)(ws + OFF_AI))[i4] = z;
  int row = i4 >> 7;
  int d4 = (i4 & 127) * 4;
  float av[4] = {a.x, a.y, a.z, a.w}, bv[4] = {b.x, b.y, b.z, b.w};
  us4 hh, hl;
#pragma unroll
  for (int j = 0; j < 4; ++j) {
    unsigned short h = f2bf(av[j]); hh[j] = h; hl[j] = f2bf(av[j] - bf2f(h));
  }
  *(us4*)(xh + (size_t)row * 1024 + d4) = hh;
  *(us4*)(xl + (size_t)row * 1024 + d4) = hl;
#pragma unroll
  for (int j = 0; j < 4; ++j) {
    unsigned short h = f2bf(bv[j]); hh[j] = h; hl[j] = f2bf(bv[j] - bf2f(h));
  }
  *(us4*)(xh + (size_t)row * 1024 + 512 + d4) = hh;
  *(us4*)(xl + (size_t)row * 1024 + 512 + d4) = hl;
  if (i4 < (B * D) / 4) {
    ((float4*)(ws + OFF_H0))[i4] = z;
    ((float4*)(ws + OFF_H1))[i4] = z;
  }
  if (i4 < 16384) ((float4*)(ws + OFF_FEAT))[i4] = z;
  if (i4 < 2048)  ((float4*)(ws + OFF_GWP))[i4] = z;
  if (i4 < B) { ws[OFF_CUM + i4] = 0.f; ws[OFF_CUM2 + i4] = 0.f; }
}

// ---------------- weight prep (R6, proven) ----------------
__global__ __launch_bounds__(256) void k_wprep(const float* __restrict__ Wqr,
                                               const float* __restrict__ Wqi,
                                               const float* __restrict__ Wkr,
                                               const float* __restrict__ Wki,
                                               const float* __restrict__ Wvr,
                                               const float* __restrict__ Wvi,
                                               float* __restrict__ ws) {
  __shared__ float lt[64][65];
  unsigned short* wh = (unsigned short*)(ws + OFF_WH);
  unsigned short* wl = (unsigned short*)(ws + OFF_WL);
  int z = blockIdx.z, m = z / 6, idx = z % 6;
  const float* Wsrc;
  switch (idx) {
    case 0:  Wsrc = Wqr; break;
    case 1:  Wsrc = Wqi; break;
    case 2:  Wsrc = Wkr; break;
    case 3:  Wsrc = Wki; break;
    case 4:  Wsrc = Wvr; break;
    default: Wsrc = Wvi; break;
  }
  Wsrc += (size_t)m * D * D;
  int k0 = blockIdx.x * 64, n0 = blockIdx.y * 64;
  int tx = threadIdx.x & 63, ty = threadIdx.x >> 6;
#pragma unroll
  for (int i = 0; i < 16; ++i) {
    int kl = ty + i * 4;
    lt[kl][tx] = Wsrc[(size_t)(k0 + kl) * D + n0 + tx];
  }
  __syncthreads();
  unsigned short* whp = wh + (size_t)z * 262144;
  unsigned short* wlp = wl + (size_t)z * 262144;
#pragma unroll
  for (int i = 0; i < 16; ++i) {
    int nl = ty + i * 4;
    float v = lt[tx][nl];
    unsigned short h = f2bf(v);
    whp[(size_t)(n0 + nl) * 512 + k0 + tx] = h;
    wlp[(size_t)(n0 + nl) * 512 + k0 + tx] = f2bf(v - bf2f(h));
  }
}

// ---------------- gwp (pre-loop only) ----------------
__global__ __launch_bounds__(256) void k_gwp(const float* __restrict__ zr,
                                             const float* __restrict__ zi,
                                             float* __restrict__ gwp) {
  int idx = blockIdx.x * 256 + threadIdx.x;
  int b = idx >> 10;
  int f = idx & 1023;
  const float* src = (f < D) ? (zr + b * S * D + f) : (zi + b * S * D + (f - D));
  float s = 0.f;
#pragma unroll 8
  for (int ss = 0; ss < S; ++ss) s += src[ss * D];
  gwp[idx] = s * (1.0f / S);
}

// ---------------- QKV GEMMs (z<24, R8-proven body) + GRU (z>=24, R7-proven body) ----------------
// grid (4, 8, 26), 256 thr. GRU blocks: gid = (z-24)*32 + y*4 + x in [0,64).
__global__ __launch_bounds__(256) void k_qkvgru(float* __restrict__ ws,
                                                const float* __restrict__ gwp,
                                                const float* __restrict__ hold,
                                                float* __restrict__ hnew,
                                                const float* __restrict__ Wih,
                                                const float* __restrict__ Whh,
                                                const float* __restrict__ bih,
                                                const float* __restrict__ bhh) {
  __shared__ __align__(16) unsigned short Ah[128 * 32], Al[128 * 32];
  __shared__ __align__(16) unsigned short Bh[128 * 32], Bl[128 * 32];
  int t = threadIdx.x;
  if (blockIdx.z >= 24) {
    // ---- GRU path: LDS overlaid on GEMM staging buffers ----
    float* xbuf = (float*)Ah;                 // 1024 floats (4 KB of 8 KB)
    float* hbuf = (float*)Al;                 // 512 floats
    float (*red)[64][4] = (float (*)[64][4])Bh;  // 4 KB of 8 KB
    int gid = (blockIdx.z - 24) * 32 + blockIdx.y * 4 + blockIdx.x;
    int b = gid >> 3;
    int c0 = (gid & 7) * 64;
    int td = t & 63, ks = t >> 6;
    for (int f = t; f < 1024; f += 256) xbuf[f] = gwp[b * 1024 + f];
    for (int d2 = t; d2 < 512; d2 += 256) hbuf[d2] = hold[b * 512 + d2];
    __syncthreads();
    float accR = 0.f, accZ = 0.f, accXn = 0.f, accHn = 0.f;
    int kbeg = ks * 384, kend = kbeg + 384;
#pragma unroll 4
    for (int kk = kbeg; kk < kend; ++kk) {
      bool ih = kk < 1024;
      float x = ih ? xbuf[kk] : hbuf[kk - 1024];
      const float* base = ih ? (Wih + (size_t)kk * 1536) : (Whh + (size_t)(kk - 1024) * 1536);
      float wr = base[c0 + td];
      float wz = base[512 + c0 + td];
      float wn = base[1024 + c0 + td];
      accR += x * wr;
      accZ += x * wz;
      if (ih) accXn += x * wn; else accHn += x * wn;
    }
    red[ks][td][0] = accR;
    red[ks][td][1] = accZ;
    red[ks][td][2] = accXn;
    red[ks][td][3] = accHn;
    __syncthreads();
    if (t < 64) {
      int c = c0 + t;
      float r_ = 0.f, z_ = 0.f, xn = 0.f, hn = 0.f;
#pragma unroll
      for (int s = 0; s < 4; ++s) {
        r_ += red[s][t][0]; z_ += red[s][t][1]; xn += red[s][t][2]; hn += red[s][t][3];
      }
      r_ += bih[c] + bhh[c];
      z_ += bih[512 + c] + bhh[512 + c];
      xn += bih[1024 + c];
      hn += bhh[1024 + c];
      float r = 1.f / (1.f + expf(-r_));
      float z = 1.f / (1.f + expf(-z_));
      float n = tanhf(xn + r * hn);
      hnew[b * 512 + c] = (1.f - z) * n + z * hbuf[c];
    }
    return;
  }
  // ---- GEMM path (R8/R11-proven) ----
  const unsigned short* xh = (const unsigned short*)(ws + OFF_XH);
  const unsigned short* xl = (const unsigned short*)(ws + OFF_XL);
  const unsigned short* wh = (const unsigned short*)(ws + OFF_WH);
  const unsigned short* wl = (const unsigned short*)(ws + OFF_WL);
  int g = blockIdx.z, m = g / 6, w6 = g % 6;
  bool qk = (w6 < 4);
  int pair = (w6 >> 1) * 2;
  int p1 = m * 6 + pair + (w6 & 1);
  int p2 = m * 6 + pair + ((w6 & 1) ^ 1);
  unsigned int xmask = (w6 & 1) ? 0u : 0x80008000u;
  const unsigned short* PH1 = wh + (size_t)p1 * 262144;
  const unsigned short* PL1 = wl + (size_t)p1 * 262144;
  const unsigned short* PH2 = wh + (size_t)p2 * 262144;
  const unsigned short* PL2 = wl + (size_t)p2 * 262144;

  int row0 = qk ? blockIdx.y * 128 : blockIdx.x * 128;
  int col0 = qk ? blockIdx.x * 128 : blockIdx.y * 128;
  int wb = qk ? col0 : row0;
  int xb = qk ? row0 : col0;
  int lane = t & 63, w = t >> 6;
  int wr = w >> 1, wc = w & 1;
  int q = lane >> 4, r = lane & 15;
  int srow = t >> 2;
  int skoff = (t & 3) * 8;
  size_t wrow1 = (size_t)(wb + srow) * 512 + skoff;
  size_t wrow2 = (size_t)(wb + 64 + srow) * 512 + skoff;
  size_t xrow1 = (size_t)(xb + srow) * 1024 + skoff;
  size_t xrow2 = (size_t)(xb + 64 + srow) * 1024 + skoff;

  floatx4 acc[4][4];
#pragma unroll
  for (int i = 0; i < 4; ++i)
#pragma unroll
    for (int j = 0; j < 4; ++j) acc[i][j] = (floatx4){0.f, 0.f, 0.f, 0.f};

  for (int k0 = 0; k0 < 1024; k0 += 32) {
    const unsigned short *WgH, *WgL;
    unsigned int xm;
    int kk = k0;
    if (k0 < 512) { WgH = PH1; WgL = PL1; xm = 0u; }
    else          { WgH = PH2; WgL = PL2; xm = xmask; kk = k0 - 512; }
    uint4 w0h = *(const uint4*)(WgH + wrow1 + kk);
    uint4 w1h = *(const uint4*)(WgH + wrow2 + kk);
    uint4 w0l = *(const uint4*)(WgL + wrow1 + kk);
    uint4 w1l = *(const uint4*)(WgL + wrow2 + kk);
    w0h.x ^= xm; w0h.y ^= xm; w0h.z ^= xm; w0h.w ^= xm;
    w1h.x ^= xm; w1h.y ^= xm; w1h.z ^= xm; w1h.w ^= xm;
    w0l.x ^= xm; w0l.y ^= xm; w0l.z ^= xm; w0l.w ^= xm;
    w1l.x ^= xm; w1l.y ^= xm; w1l.z ^= xm; w1l.w ^= xm;
    uint4 x0h = *(const uint4*)(xh + xrow1 + k0);
    uint4 x1h = *(const uint4*)(xh + xrow2 + k0);
    uint4 x0l = *(const uint4*)(xl + xrow1 + k0);
    uint4 x1l = *(const uint4*)(xl + xrow2 + k0);
    if (qk) {
      *(uint4*)(Ah + srow * 32 + skoff) = x0h;
      *(uint4*)(Ah + (64 + srow) * 32 + skoff) = x1h;
      *(uint4*)(Al + srow * 32 + skoff) = x0l;
      *(uint4*)(Al + (64 + srow) * 32 + skoff) = x1l;
      *(uint4*)(Bh + srow * 32 + skoff) = w0h;
      *(uint4*)(Bh + (64 + srow) * 32 + skoff) = w1h;
      *(uint4*)(Bl + srow * 32 + skoff) = w0l;
      *(uint4*)(Bl + (64 + srow) * 32 + skoff) = w1l;
    } else {
      *(uint4*)(Ah + srow * 32 + skoff) = w0h;
      *(uint4*)(Ah + (64 + srow) * 32 + skoff) = w1h;
      *(uint4*)(Al + srow * 32 + skoff) = w0l;
      *(uint4*)(Al + (64 + srow) * 32 + skoff) = w1l;
      *(uint4*)(Bh + srow * 32 + skoff) = x0h;
      *(uint4*)(Bh + (64 + srow) * 32 + skoff) = x1h;
      *(uint4*)(Bl + srow * 32 + skoff) = x0l;
      *(uint4*)(Bl + (64 + srow) * 32 + skoff) = x1l;
    }
    __syncthreads();
    s8v ah[4], al[4], bh[4], bl[4];
#pragma unroll
    for (int i = 0; i < 4; ++i) {
      int ro = (wr * 64 + i * 16 + r) * 32 + q * 8;
      ah[i] = *(const s8v*)((const short*)Ah + ro);
      al[i] = *(const s8v*)((const short*)Al + ro);
    }
#pragma unroll
    for (int j = 0; j < 4; ++j) {
      int ro = (wc * 64 + j * 16 + r) * 32 + q * 8;
      bh[j] = *(const s8v*)((const short*)Bh + ro);
      bl[j] = *(const s8v*)((const short*)Bl + ro);
    }
#pragma unroll
    for (int i = 0; i < 4; ++i)
#pragma unroll
      for (int j = 0; j < 4; ++j) {
        acc[i][j] = __builtin_amdgcn_mfma_f32_16x16x32_bf16(ah[i], bh[j], acc[i][j], 0, 0, 0);
        acc[i][j] = __builtin_amdgcn_mfma_f32_16x16x32_bf16(ah[i], bl[j], acc[i][j], 0, 0, 0);
        acc[i][j] = __builtin_amdgcn_mfma_f32_16x16x32_bf16(al[i], bh[j], acc[i][j], 0, 0, 0);
      }
    __syncthreads();
  }
  unsigned short *dh, *dl;
  size_t base;
  int half = 0;
  if (qk) {
    if (w6 < 2) { dh = (unsigned short*)(ws + OFF_QCH); dl = (unsigned short*)(ws + OFF_QCL); }
    else        { dh = (unsigned short*)(ws + OFF_KCH); dl = (unsigned short*)(ws + OFF_KCL); }
    half = (w6 & 1) * 512;
    base = (size_t)m * 1024 * 1024;
  } else {
    dh = (unsigned short*)(ws + OFF_VTH);
    dl = (unsigned short*)(ws + OFF_VTL);
    base = (size_t)((w6 & 1) * 4 + m) * 512 * 1024;
  }
#pragma unroll
  for (int i = 0; i < 4; ++i)
#pragma unroll
    for (int j = 0; j < 4; ++j) {
      int rowb = row0 + wr * 64 + i * 16 + q * 4;
      int colb = col0 + wc * 64 + j * 16 + r;
#pragma unroll
      for (int reg = 0; reg < 4; ++reg) {
        float v = acc[i][j][reg];
        unsigned short h = f2bf(v);
        size_t idx = base + (size_t)(rowb + reg) * 1024 + half + colb;
        dh[idx] = h;
        dl[idx] = f2bf(v - bf2f(h));
      }
    }
}

// ---------------- attn: scores (bf16x3 MFMA) + softmax -> P hi/lo (R11, proven) ----------------
// grid 64 (mb*2 + rowhalf), 256 thr. 64x128 tile: 4 col-waves x (4 i-frag, 2 j-frag).
__global__ __launch_bounds__(256) void k_attn(float* __restrict__ ws) {
  __shared__ __align__(16) unsigned short Ah[64 * 32], Al[64 * 32];
  __shared__ __align__(16) unsigned short Bh[128 * 32], Bl[128 * 32];
  __shared__ float rmax[64][4];
  __shared__ float rsum[64][4];
  const unsigned short* qch = (const unsigned short*)(ws + OFF_QCH);
  const unsigned short* qcl = (const unsigned short*)(ws + OFF_QCL);
  const unsigned short* kch = (const unsigned short*)(ws + OFF_KCH);
  const unsigned short* kcl = (const unsigned short*)(ws + OFF_KCL);
  unsigned short* ph = (unsigned short*)(ws + OFF_PH);
  unsigned short* pl = (unsigned short*)(ws + OFF_PL);
  int blk = blockIdx.x, mb = blk >> 1, half = blk & 1;
  size_t gbase = (size_t)mb * 128 * 1024;
  int t = threadIdx.x, lane = t & 63, wc = t >> 6;
  int q = lane >> 4, r = lane & 15;
  int srow = t >> 2;                 // 0..63
  int skoff = (t & 3) * 8;
  size_t arow = gbase + (size_t)(half * 64 + srow) * 1024 + skoff;  // Q rows (64)
  size_t brow1 = gbase + (size_t)srow * 1024 + skoff;               // K rows (all 128)
  size_t brow2 = gbase + (size_t)(64 + srow) * 1024 + skoff;

  floatx4 acc[4][2];
#pragma unroll
  for (int i = 0; i < 4; ++i)
#pragma unroll
    for (int j = 0; j < 2; ++j) acc[i][j] = (floatx4){0.f, 0.f, 0.f, 0.f};

  for (int k0 = 0; k0 < 1024; k0 += 32) {
    uint4 a0h = *(const uint4*)(qch + arow + k0);
    uint4 a0l = *(const uint4*)(qcl + arow + k0);
    uint4 b0h = *(const uint4*)(kch + brow1 + k0);
    uint4 b1h = *(const uint4*)(kch + brow2 + k0);
    uint4 b0l = *(const uint4*)(kcl + brow1 + k0);
    uint4 b1l = *(const uint4*)(kcl + brow2 + k0);
    *(uint4*)(Ah + srow * 32 + skoff) = a0h;
    *(uint4*)(Al + srow * 32 + skoff) = a0l;
    *(uint4*)(Bh + srow * 32 + skoff) = b0h;
    *(uint4*)(Bh + (64 + srow) * 32 + skoff) = b1h;
    *(uint4*)(Bl + srow * 32 + skoff) = b0l;
    *(uint4*)(Bl + (64 + srow) * 32 + skoff) = b1l;
    __syncthreads();
    s8v ah[4], al[4], bh[2], bl[2];
#pragma unroll
    for (int i = 0; i < 4; ++i) {
      int ro = (i * 16 + r) * 32 + q * 8;
      ah[i] = *(const s8v*)((const short*)Ah + ro);
      al[i] = *(const s8v*)((const short*)Al + ro);
    }
#pragma unroll
    for (int j = 0; j < 2; ++j) {
      int ro = (wc * 32 + j * 16 + r) * 32 + q * 8;
      bh[j] = *(const s8v*)((const short*)Bh + ro);
      bl[j] = *(const s8v*)((const short*)Bl + ro);
    }
#pragma unroll
    for (int i = 0; i < 4; ++i)
#pragma unroll
      for (int j = 0; j < 2; ++j) {
        acc[i][j] = __builtin_amdgcn_mfma_f32_16x16x32_bf16(ah[i], bh[j], acc[i][j], 0, 0, 0);
        acc[i][j] = __builtin_amdgcn_mfma_f32_16x16x32_bf16(ah[i], bl[j], acc[i][j], 0, 0, 0);
        acc[i][j] = __builtin_amdgcn_mfma_f32_16x16x32_bf16(al[i], bh[j], acc[i][j], 0, 0, 0);
      }
    __syncthreads();
  }
#pragma unroll
  for (int i = 0; i < 4; ++i)
#pragma unroll
    for (int j = 0; j < 2; ++j)
#pragma unroll
      for (int reg = 0; reg < 4; ++reg) acc[i][j][reg] *= SCALE;
#pragma unroll
  for (int i = 0; i < 4; ++i)
#pragma unroll
    for (int reg = 0; reg < 4; ++reg) {
      float mx = fmaxf(acc[i][0][reg], acc[i][1][reg]);
      for (int o = 1; o < 16; o <<= 1) mx = fmaxf(mx, __shfl_xor(mx, o));
      if (r == 0) rmax[i * 16 + q * 4 + reg][wc] = mx;
    }
  __syncthreads();
#pragma unroll
  for (int i = 0; i < 4; ++i)
#pragma unroll
    for (int reg = 0; reg < 4; ++reg) {
      int row = i * 16 + q * 4 + reg;
      float gmx = fmaxf(fmaxf(rmax[row][0], rmax[row][1]),
                        fmaxf(rmax[row][2], rmax[row][3]));
      float sm = 0.f;
#pragma unroll
      for (int j = 0; j < 2; ++j) {
        float e = __expf(acc[i][j][reg] - gmx);
        acc[i][j][reg] = e;
        sm += e;
      }
      for (int o = 1; o < 16; o <<= 1) sm += __shfl_xor(sm, o);
      if (r == 0) rsum[row][wc] = sm;
    }
  __syncthreads();
#pragma unroll
  for (int i = 0; i < 4; ++i)
#pragma unroll
    for (int reg = 0; reg < 4; ++reg) {
      int row = i * 16 + q * 4 + reg;
      float inv = 1.f / (rsum[row][0] + rsum[row][1] + rsum[row][2] + rsum[row][3]);
      size_t rb = (size_t)(mb * 128 + half * 64 + row) * 128;
#pragma unroll
      for (int j = 0; j < 2; ++j) {
        float p = acc[i][j][reg] * inv;
        unsigned short h = f2bf(p);
        size_t idx = rb + wc * 32 + j * 16 + r;
        ph[idx] = h;
        pl[idx] = f2bf(p - bf2f(h));
      }
    }
}

// ---------------- PV: O = P @ Vt^T (bf16x3 MFMA), fp32 out (R8/R11, proven) ----------------
__global__ __launch_bounds__(256) void k_pv(float* __restrict__ ws) {
  __shared__ __align__(16) unsigned short Ph_[128 * 32], Pl_[128 * 32];
  __shared__ __align__(16) unsigned short VrH[128 * 32], VrL[128 * 32];
  __shared__ __align__(16) unsigned short ViH[128 * 32], ViL[128 * 32];
  const unsigned short* ph = (const unsigned short*)(ws + OFF_PH);
  const unsigned short* pl = (const unsigned short*)(ws + OFF_PL);
  const unsigned short* vth = (const unsigned short*)(ws + OFF_VTH);
  const unsigned short* vtl = (const unsigned short*)(ws + OFF_VTL);
  int mb = blockIdx.y, m = mb >> 3, b = mb & 7;
  int col0 = blockIdx.x * 128;
  int t = threadIdx.x, lane = t & 63, w = t >> 6;
  int wr = w >> 1, wc = w & 1;
  int q = lane >> 4, r = lane & 15;
  int srow = t >> 2;
  int skoff = (t & 3) * 8;
  size_t prow1 = (size_t)(mb * 128 + srow) * 128 + skoff;
  size_t prow2 = (size_t)(mb * 128 + 64 + srow) * 128 + skoff;
  size_t vbr1 = ((size_t)(m * 512) + col0 + srow) * 1024 + b * 128 + skoff;
  size_t vbr2 = ((size_t)(m * 512) + col0 + 64 + srow) * 1024 + b * 128 + skoff;
  size_t vplane_i = (size_t)4 * 512 * 1024;

  floatx4 accR[4][4], accI[4][4];
#pragma unroll
  for (int i = 0; i < 4; ++i)
#pragma unroll
    for (int j = 0; j < 4; ++j) {
      accR[i][j] = (floatx4){0.f, 0.f, 0.f, 0.f};
      accI[i][j] = (floatx4){0.f, 0.f, 0.f, 0.f};
    }

  for (int k0 = 0; k0 < 128; k0 += 32) {
    *(uint4*)(Ph_ + srow * 32 + skoff) = *(const uint4*)(ph + prow1 + k0);
    *(uint4*)(Ph_ + (64 + srow) * 32 + skoff) = *(const uint4*)(ph + prow2 + k0);
    *(uint4*)(Pl_ + srow * 32 + skoff) = *(const uint4*)(pl + prow1 + k0);
    *(uint4*)(Pl_ + (64 + srow) * 32 + skoff) = *(const uint4*)(pl + prow2 + k0);
    *(uint4*)(VrH + srow * 32 + skoff) = *(const uint4*)(vth + vbr1 + k0);
    *(uint4*)(VrH + (64 + srow) * 32 + skoff) = *(const uint4*)(vth + vbr2 + k0);
    *(uint4*)(VrL + srow * 32 + skoff) = *(const uint4*)(vtl + vbr1 + k0);
    *(uint4*)(VrL + (64 + srow) * 32 + skoff) = *(const uint4*)(vtl + vbr2 + k0);
    *(uint4*)(ViH + srow * 32 + skoff) = *(const uint4*)(vth + vplane_i + vbr1 + k0);
    *(uint4*)(ViH + (64 + srow) * 32 + skoff) = *(const uint4*)(vth + vplane_i + vbr2 + k0);
    *(uint4*)(ViL + srow * 32 + skoff) = *(const uint4*)(vtl + vplane_i + vbr1 + k0);
    *(uint4*)(ViL + (64 + srow) * 32 + skoff) = *(const uint4*)(vtl + vplane_i + vbr2 + k0);
    __syncthreads();
    s8v ah[4], al[4];
#pragma unroll
    for (int i = 0; i < 4; ++i) {
      int ro = (wr * 64 + i * 16 + r) * 32 + q * 8;
      ah[i] = *(const s8v*)((const short*)Ph_ + ro);
      al[i] = *(const s8v*)((const short*)Pl_ + ro);
    }
#pragma unroll
    for (int j = 0; j < 4; ++j) {
      int ro = (wc * 64 + j * 16 + r) * 32 + q * 8;
      s8v vrh = *(const s8v*)((const short*)VrH + ro);
      s8v vrl = *(const s8v*)((const short*)VrL + ro);
      s8v vih = *(const s8v*)((const short*)ViH + ro);
      s8v vil = *(const s8v*)((const short*)ViL + ro);
#pragma unroll
      for (int i = 0; i < 4; ++i) {
        accR[i][j] = __builtin_amdgcn_mfma_f32_16x16x32_bf16(ah[i], vrh, accR[i][j], 0, 0, 0);
        accR[i][j] = __builtin_amdgcn_mfma_f32_16x16x32_bf16(ah[i], vrl, accR[i][j], 0, 0, 0);
        accR[i][j] = __builtin_amdgcn_mfma_f32_16x16x32_bf16(al[i], vrh, accR[i][j], 0, 0, 0);
        accI[i][j] = __builtin_amdgcn_mfma_f32_16x16x32_bf16(ah[i], vih, accI[i][j], 0, 0, 0);
        accI[i][j] = __builtin_amdgcn_mfma_f32_16x16x32_bf16(ah[i], vil, accI[i][j], 0, 0, 0);
        accI[i][j] = __builtin_amdgcn_mfma_f32_16x16x32_bf16(al[i], vih, accI[i][j], 0, 0, 0);
      }
    }
    __syncthreads();
  }
  float* orp = ws + OFF_OR + (size_t)mb * 128 * 512;
  float* oip = ws + OFF_OI + (size_t)mb * 128 * 512;
#pragma unroll
  for (int i = 0; i < 4; ++i)
#pragma unroll
    for (int j = 0; j < 4; ++j) {
      int rowb = wr * 64 + i * 16 + q * 4;
      int colb = col0 + wc * 64 + j * 16 + r;
#pragma unroll
      for (int reg = 0; reg < 4; ++reg) {
        orp[(size_t)(rowb + reg) * 512 + colb] = accR[i][j][reg];
        oip[(size_t)(rowb + reg) * 512 + colb] = accI[i][j][reg];
      }
    }
}

// ---------------- ModReLU + ComplexLayerNorm + feat partials (fused, R9/R11) ----------------
__global__ __launch_bounds__(256) void k_modlnfeat(float* __restrict__ ws,
                                                   const float* __restrict__ mod_bias,
                                                   const float* __restrict__ ln_scale,
                                                   const float* __restrict__ ln_shift) {
  int blk = blockIdx.x;
  int mb = blk >> 2, grp = blk & 3;
  int m = mb >> 3;
  int t = threadIdx.x, w = t >> 6, l = t & 63;
  int e0 = l * 8;
  float mb_[8], lsc[8], lsh[8];
  *(float4*)&mb_[0] = *(const float4*)(mod_bias + m * 512 + e0);
  *(float4*)&mb_[4] = *(const float4*)(mod_bias + m * 512 + e0 + 4);
  *(float4*)&lsc[0] = *(const float4*)(ln_scale + m * 512 + e0);
  *(float4*)&lsc[4] = *(const float4*)(ln_scale + m * 512 + e0 + 4);
  *(float4*)&lsh[0] = *(const float4*)(ln_shift + m * 512 + e0);
  *(float4*)&lsh[4] = *(const float4*)(ln_shift + m * 512 + e0 + 4);
  float featR[8] = {}, featI[8] = {};
  for (int it = 0; it < 8; ++it) {
    int s = grp * 32 + it * 4 + w;
    float* orp = ws + OFF_OR + ((size_t)mb * 128 + s) * 512 + e0;
    float* oip = ws + OFF_OI + ((size_t)mb * 128 + s) * 512 + e0;
    float orv[8], oiv[8], magv[8];
    *(float4*)&orv[0] = *(const float4*)orp;
    *(float4*)&orv[4] = *(const float4*)(orp + 4);
    *(float4*)&oiv[0] = *(const float4*)oip;
    *(float4*)&oiv[4] = *(const float4*)(oip + 4);
    float sum = 0.f, sumsq = 0.f;
#pragma unroll
    for (int j = 0; j < 8; ++j) {
      float o_r = orv[j], o_i = oiv[j];
      float mag = sqrtf(o_r * o_r + o_i * o_i) + EPS;
      float g = fmaxf(mag + mb_[j], 0.f) / mag;
      o_r *= g; o_i *= g;
      orv[j] = o_r; oiv[j] = o_i;
      float mag2 = sqrtf(o_r * o_r + o_i * o_i) + EPS;
      magv[j] = mag2;
      sum += mag2;
      sumsq += mag2 * mag2;
    }
    for (int o = 1; o < 64; o <<= 1) {
      sum += __shfl_xor(sum, o);
      sumsq += __shfl_xor(sumsq, o);
    }
    float mu = sum * (1.f / D);
    float var = (sumsq - (float)D * mu * mu) * (1.f / (D - 1));
    float inv = 1.f / sqrtf(var + EPS);
#pragma unroll
    for (int j = 0; j < 8; ++j) {
      float nm = (magv[j] - mu) * inv * lsc[j] + lsh[j];
      float hyp = magv[j] - EPS;
      float cp, sp;
      if (hyp > 0.f) { cp = orv[j] / hyp; sp = oiv[j] / hyp; }
      else           { cp = 1.f;          sp = 0.f; }
      orv[j] = nm * cp;
      oiv[j] = nm * sp;
      featR[j] += orv[j];
      featI[j] += oiv[j];
    }
    *(float4*)orp = *(float4*)&orv[0];
    *(float4*)(orp + 4) = *(float4*)&orv[4];
    *(float4*)oip = *(float4*)&oiv[0];
    *(float4*)(oip + 4) = *(float4*)&oiv[4];
  }
  float* fb = ws + OFF_FEAT + (size_t)mb * 1024;
#pragma unroll
  for (int j = 0; j < 8; ++j) {
    atomicAdd(fb + e0 + j, featR[j] * (1.0f / S));
    atomicAdd(fb + 512 + e0 + j, featI[j] * (1.0f / S));
  }
}

// ---------------- wsel (R1) + zero FEAT/GWP for next step (R9) ----------------
__global__ __launch_bounds__(256) void k_wsel(float* __restrict__ ws,
                                              const float* __restrict__ hnew,
                                              const float* __restrict__ bias_W,
                                              const float* __restrict__ bias_b,
                                              const float* __restrict__ w_sal) {
  __shared__ float mb_s[B][M];
  __shared__ float sal_s[M][B];
  int t = threadIdx.x;
  int p = t >> 3, l = t & 7;
  {
    int b = p >> 2, m = p & 3;
    float s = 0.f;
    for (int d2 = l; d2 < D; d2 += 8) s += hnew[b * D + d2] * bias_W[d2 * M + m];
    for (int o = 1; o < 8; o <<= 1) s += __shfl_xor(s, o);
    if (l == 0) mb_s[b][m] = s + bias_b[m];
  }
  {
    int m = p >> 3, b = p & 7;
    float s = 0.f;
    for (int f = l; f < 2 * D; f += 8) s += ws[OFF_FEAT + (m * B + b) * 2 * D + f] * w_sal[m * 2 * D + f];
    for (int o = 1; o < 8; o <<= 1) s += __shfl_xor(s, o);
    if (l == 0) sal_s[m][b] = s;
  }
  __syncthreads();
  if (t < B) {
    int b = t;
    float lg[M], mx = -1e30f;
#pragma unroll
    for (int m = 0; m < M; ++m) { lg[m] = sal_s[m][b] + mb_s[b][m]; mx = fmaxf(mx, lg[m]); }
    float sm = 0.f;
#pragma unroll
    for (int m = 0; m < M; ++m) { lg[m] = expf(lg[m] - mx); sm += lg[m]; }
    float inv = 1.f / sm;
#pragma unroll
    for (int m = 0; m < M; ++m) ws[OFF_W + m * B + b] = lg[m] * inv;
  }
  float4 z4 = {0.f, 0.f, 0.f, 0.f};
  for (int i = t; i < 16384; i += 256) ((float4*)(ws + OFF_FEAT))[i] = z4;
  for (int i = t; i < 2048; i += 256) ((float4*)(ws + OFF_GWP))[i] = z4;
}

// ---------------- bcast (fp32 Z + bf16 Xcat) + gwp partial accumulation (R9) ----------------
__global__ __launch_bounds__(256) void k_bcast(float* __restrict__ ws) {
  __shared__ float pr[1024];
  unsigned short* xh = (unsigned short*)(ws + OFF_XH);
  unsigned short* xl = (unsigned short*)(ws + OFF_XL);
  int t = threadIdx.x;
  int i4 = blockIdx.x * 256 + t;
  int b = i4 >> 14;
  int l = t & 127;
  float w0 = ws[OFF_W + 0 * B + b], w1 = ws[OFF_W + 1 * B + b];
  float w2 = ws[OFF_W + 2 * B + b], w3 = ws[OFF_W + 3 * B + b];
  const float4* mr = (const float4*)(ws + OFF_OR);
  const float4* mi = (const float4*)(ws + OFF_OI);
  const int MS = BSD / 4;
  int row = i4 >> 7;
  int d4 = (i4 & 127) * 4;
  float4 r0 = mr[i4], r1 = mr[i4 + MS], r2 = mr[i4 + 2 * MS], r3 = mr[i4 + 3 * MS];
  float gvR[4];
  gvR[0] = w0 * r0.x + w1 * r1.x + w2 * r2.x + w3 * r3.x;
  gvR[1] = w0 * r0.y + w1 * r1.y + w2 * r2.y + w3 * r3.y;
  gvR[2] = w0 * r0.z + w1 * r1.z + w2 * r2.z + w3 * r3.z;
  gvR[3] = w0 * r0.w + w1 * r1.w + w2 * r2.w + w3 * r3.w;
  ((float4*)(ws + OFF_ZR))[i4] = (float4){gvR[0], gvR[1], gvR[2], gvR[3]};
  us4 hh, hl;
#pragma unroll
  for (int j = 0; j < 4; ++j) {
    unsigned short h = f2bf(gvR[j]); hh[j] = h; hl[j] = f2bf(gvR[j] - bf2f(h));
  }
  *(us4*)(xh + (size_t)row * 1024 + d4) = hh;
  *(us4*)(xl + (size_t)row * 1024 + d4) = hl;
  float4 s0 = mi[i4], s1 = mi[i4 + MS], s2 = mi[i4 + 2 * MS], s3 = mi[i4 + 3 * MS];
  float gvI[4];
  gvI[0] = w0 * s0.x + w1 * s1.x + w2 * s2.x + w3 * s3.x;
  gvI[1] = w0 * s0.y + w1 * s1.y + w2 * s2.y + w3 * s3.y;
  gvI[2] = w0 * s0.z + w1 * s1.z + w2 * s2.z + w3 * s3.z;
  gvI[3] = w0 * s0.w + w1 * s1.w + w2 * s2.w + w3 * s3.w;
  ((float4*)(ws + OFF_ZI))[i4] = (float4){gvI[0], gvI[1], gvI[2], gvI[3]};
#pragma unroll
  for (int j = 0; j < 4; ++j) {
    unsigned short h = f2bf(gvI[j]); hh[j] = h; hl[j] = f2bf(gvI[j] - bf2f(h));
  }
  *(us4*)(xh + (size_t)row * 1024 + 512 + d4) = hh;
  *(us4*)(xl + (size_t)row * 1024 + 512 + d4) = hl;
  if (t < 128) {
#pragma unroll
    for (int j = 0; j < 4; ++j) { pr[l * 4 + j] = gvR[j]; pr[512 + l * 4 + j] = gvI[j]; }
  }
  __syncthreads();
  if (t >= 128) {
#pragma unroll
    for (int j = 0; j < 4; ++j) { pr[l * 4 + j] += gvR[j]; pr[512 + l * 4 + j] += gvI[j]; }
  }
  __syncthreads();
  for (int pp = t; pp < 1024; pp += 256)
    atomicAdd(ws + OFF_GWP + b * 1024 + pp, pr[pp] * (1.0f / S));
}

// ---------------- halt + ACT accumulate (fused; cum double-buffered) (R9) ----------------
__global__ __launch_bounds__(256) void k_acchalt(float* __restrict__ ws,
                                                 const float* __restrict__ w_halt,
                                                 const float* __restrict__ b_halt,
                                                 const float* __restrict__ cumr,
                                                 float* __restrict__ cumw) {
  __shared__ float sred[4];
  int t = threadIdx.x;
  int i4 = blockIdx.x * 256 + t;
  int b = i4 >> 14;
  float4 g = *(const float4*)(ws + OFF_GWP + b * 1024 + t * 4);
  float4 wv = *(const float4*)(w_halt + t * 4);
  float s = g.x * wv.x + g.y * wv.y + g.z * wv.z + g.w * wv.w;
  for (int o = 1; o < 64; o <<= 1) s += __shfl_xor(s, o);
  if ((t & 63) == 0) sred[t >> 6] = s;
  __syncthreads();
  float tot = sred[0] + sred[1] + sred[2] + sred[3];
  float p = 1.f / (1.f + expf(-(tot + b_halt[0])));
  float cum = cumr[b];
  float still = (cum < THRESH) ? 1.f : 0.f;
  bool nh = ((cum + p) >= THRESH) && (cum < THRESH);
  float wt = (nh ? (1.f - cum) : p) * still;
  if (((blockIdx.x & 63) == 0) && t == 0) cumw[b] = cum + wt;
  float4 z = ((const float4*)(ws + OFF_ZR))[i4];
  float4 a = ((float4*)(ws + OFF_AR))[i4];
  a.x += wt * z.x; a.y += wt * z.y; a.z += wt * z.z; a.w += wt * z.w;
  ((float4*)(ws + OFF_AR))[i4] = a;
  z = ((const float4*)(ws + OFF_ZI))[i4];
  a = ((float4*)(ws + OFF_AI))[i4];
  a.x += wt * z.x; a.y += wt * z.y; a.z += wt * z.z; a.w += wt * z.w;
  ((float4*)(ws + OFF_AI))[i4] = a;
}

// ---------------- output (R1) ----------------
__global__ __launch_bounds__(256) void k_out(const float* __restrict__ ws,
                                             float* __restrict__ out) {
  int i4 = blockIdx.x * 256 + threadIdx.x;
  ((float4*)out)[i4] = ((const float4*)(ws + OFF_AR))[i4];
  ((float4*)out)[i4 + BSD / 4] = ((const float4*)(ws + OFF_AI))[i4];
}

extern "C" void kernel_launch(void* const* d_in, const int* in_sizes, int n_in,
                              void* d_out, int out_size, void* d_ws, size_t ws_size,
                              hipStream_t stream) {
  (void)in_sizes; (void)n_in; (void)out_size; (void)ws_size;
  const float* x_real  = (const float*)d_in[0];
  const float* x_imag  = (const float*)d_in[1];
  const float* Wq_r    = (const float*)d_in[2];
  const float* Wq_i    = (const float*)d_in[3];
  const float* Wk_r    = (const float*)d_in[4];
  const float* Wk_i    = (const float*)d_in[5];
  const float* Wv_r    = (const float*)d_in[6];
  const float* Wv_i    = (const float*)d_in[7];
  const float* mod_bias = (const float*)d_in[8];
  const float* ln_scale = (const float*)d_in[9];
  const float* ln_shift = (const float*)d_in[10];
  const float* w_sal   = (const float*)d_in[11];
  const float* gru_Wih = (const float*)d_in[12];
  const float* gru_Whh = (const float*)d_in[13];
  const float* gru_bih = (const float*)d_in[14];
  const float* gru_bhh = (const float*)d_in[15];
  const float* bias_W  = (const float*)d_in[16];
  const float* bias_b  = (const float*)d_in[17];
  const float* w_halt  = (const float*)d_in[18];
  const float* b_halt  = (const float*)d_in[19];
  float* ws = (float*)d_ws;
  float* out = (float*)d_out;

  k_wprep<<<dim3(8, 8, 24), 256, 0, stream>>>(Wq_r, Wq_i, Wk_r, Wk_i, Wv_r, Wv_i, ws);
  k_init<<<512, 256, 0, stream>>>(x_real, x_imag, ws);
  k_gwp<<<32, 256, 0, stream>>>(ws + OFF_ZR, ws + OFF_ZI, ws + OFF_GWP);
  for (int step = 0; step < DEPTH; ++step) {
    const float* hold = ws + ((step & 1) ? OFF_H1 : OFF_H0);
    float* hnew = ws + ((step & 1) ? OFF_H0 : OFF_H1);
    const float* cumr = ws + ((step & 1) ? OFF_CUM2 : OFF_CUM);
    float* cumw = ws + ((step & 1) ? OFF_CUM : OFF_CUM2);
    k_qkvgru<<<dim3(4, 8, 26), 256, 0, stream>>>(ws, ws + OFF_GWP, hold, hnew,
                                                 gru_Wih, gru_Whh, gru_bih, gru_bhh);
    k_attn<<<64, 256, 0, stream>>>(ws);
    k_pv<<<dim3(4, 32), 256, 0, stream>>>(ws);
    k_modlnfeat<<<128, 256, 0, stream>>>(ws, mod_bias, ln_scale, ln_shift);
    k_wsel<<<1, 256, 0, stream>>>(ws, hnew, bias_W, bias_b, w_sal);
    k_bcast<<<512, 256, 0, stream>>>(ws);
    k_acchalt<<<512, 256, 0, stream>>>(ws, w_halt, b_halt, cumr, cumw);
  }
  k_out<<<512, 256, 0, stream>>>(ws, out);
}